// Round 6
// baseline (1615.315 us; speedup 1.0000x reference)
//
#include <hip/hip_runtime.h>

// RNN: S=512, B=128, I=256, H=512, O=128
// R10: LDS broadcast staging. R9 regressed (1171->1413us) because every wave
// read all 16 h-frags from global: 8 waves x 16KB = 128KB/CU/step of L2
// traffic (L1 dead: acquire fence invalidates it every step). Fix: h frags
// broadcast through LDS (double-buffered 2x16KB):
//   - own half: each wave ds_writes its computed frag at epilogue; next step
//     all waves ds_read it. Zero global traffic for own half.
//   - partner half: each wave stages 1KB (one global_load_dwordx4) ->
//     ds_write -> barrier -> all waves ds_read. 8KB/CU/step from L2.
// Per-CU global reads: 128KB -> ~16KB/step; the 128KB broadcast moves to
// LDS (~512cyc @256B/cyc, under the ~1000cyc MFMA pipe).
// Step schedule: ds_read own frags | poll+fence | issue partner stage load |
// acc init from xh + xh[t+1] prefetch | own MFMAs (cover stage latency) |
// stage ds_write + barrier | ds_read partner + partner MFMAs | tanh epilogue
// + global h store + ds_write own frag (next buffer) | barrier + flag.
// R9 (kept): t=0 read->barrier->store race fix. R8 (kept): 8 waves
// (2/SIMD), 32 W_hh frags = 128 AGPRs/wave, wave W owns cols half*256+W*32
// == frag half*8+W. R7 (kept): relaxed poll + one acquire fence; agent-scope
// release/acquire flag per (g,half); h stored into consumed xh window in
// MFMA A-frag layout (== hs layout for out_gemm). R5 (kept): fast tanh,
// v_cvt_pk_bf16_f32, xh folded into acc init.

typedef __attribute__((ext_vector_type(8))) short short8;   // 8 bf16
typedef __attribute__((ext_vector_type(4))) float f32x4;    // MFMA C/D
typedef __attribute__((ext_vector_type(2))) unsigned int uint2v;

__device__ __forceinline__ unsigned short f32_to_bf16(float f) {
  unsigned int u = __float_as_uint(f);
  u += 0x7FFFu + ((u >> 16) & 1u);
  return (unsigned short)(u >> 16);
}

// tanh(x) = 1 - 2/(e^{2x}+1) = 1 - 2*rcp(2^{2*log2e*x}+1).
__device__ __forceinline__ float tanh_fast(float x) {
  float e = __builtin_amdgcn_exp2f(x * 2.885390081777927f);  // 2*log2(e)
  float r = __builtin_amdgcn_rcpf(e + 1.0f);
  return __builtin_fmaf(-2.0f, r, 1.0f);
}

// D[15:0] = bf16(lo), D[31:16] = bf16(hi)
__device__ __forceinline__ unsigned cvt_pk_bf16(float lo, float hi) {
  unsigned r;
  asm("v_cvt_pk_bf16_f32 %0, %1, %2" : "=v"(r) : "v"(lo), "v"(hi));
  return r;
}

__device__ __forceinline__ float bf16_lo(unsigned u) {
  return __uint_as_float(u << 16);
}
__device__ __forceinline__ float bf16_hi(unsigned u) {
  return __uint_as_float(u & 0xFFFF0000u);
}

// ---------------------------------------------------------------------------
// Pack K x N fp32 row-major -> bf16 MFMA fragment tiles.
// Tile (nt,kt): lane holds W[k=kt*32+(lane>>4)*8+j][n=nt*16+(lane&15)],
// stored P[tile*512 + lane*8 + j], tile = nt*(K/32)+kt.
// ---------------------------------------------------------------------------
__global__ void pack_b_kernel(const float* __restrict__ W,
                              unsigned short* __restrict__ P, int K, int N) {
  int tid  = blockIdx.x * 256 + threadIdx.x;
  int lane = tid & 63;
  int tile = tid >> 6;
  int nKt  = K >> 5;
  int nTiles = (N >> 4) * nKt;
  if (tile >= nTiles) return;
  int nt = tile / nKt;
  int kt = tile - nt * nKt;
  int n  = (nt << 4) + (lane & 15);
  int k0 = (kt << 5) + ((lane >> 4) << 3);
  unsigned short* dst = P + (size_t)tile * 512 + lane * 8;
#pragma unroll
  for (int j = 0; j < 8; ++j)
    dst[j] = f32_to_bf16(W[(size_t)(k0 + j) * N + n]);
}

__global__ void init_flags_kernel(int* __restrict__ flags) {
  if (threadIdx.x < 16) flags[threadIdx.x * 32] = 0;
}

// ---------------------------------------------------------------------------
// Phase 1: xh = x@W_xh + b_h, swapped-operand MFMA; stored pre-swizzled:
// xh_s[((t*8+g)*4 + by)*2048 + lane*32 + nt*4 + r] =
//   xh[t][g*16 + (lane&15)][by*128 + nt*16 + (lane>>4)*4 + r]
// grid 1024; by-loop internal so x is read from HBM exactly once.
// ---------------------------------------------------------------------------
__global__ __launch_bounds__(256) void xh_gemm_kernel(
    const float* __restrict__ x, const unsigned short* __restrict__ Wxh_p,
    const float* __restrict__ b_h, unsigned short* __restrict__ xh_s) {
  __shared__ __align__(16) unsigned short Abuf[64 * 264];
  const int tid = threadIdx.x;
  const int m0 = blockIdx.x * 64;

#pragma unroll
  for (int i = 0; i < 16; ++i) {
    int flat = i * 1024 + tid * 4;
    int row = flat >> 8, col = flat & 255;
    float4 v = *(const float4*)(x + (size_t)(m0 + row) * 256 + col);
    ushort4 u;
    u.x = f32_to_bf16(v.x); u.y = f32_to_bf16(v.y);
    u.z = f32_to_bf16(v.z); u.w = f32_to_bf16(v.w);
    *(ushort4*)(Abuf + row * 264 + col) = u;
  }
  __syncthreads();

  const int w2 = tid >> 6, lane = tid & 63;
  const int quad = lane >> 4, col16 = lane & 15;
  const int aBase = (w2 * 16 + col16) * 264 + quad * 8;
  const int t = (m0 + w2 * 16) >> 7;
  const int g = ((m0 + w2 * 16) & 127) >> 4;

  for (int by = 0; by < 4; ++by) {
    f32x4 acc[8];
#pragma unroll
    for (int nt = 0; nt < 8; ++nt) acc[nt] = (f32x4){0.f,0.f,0.f,0.f};
#pragma unroll
    for (int kt = 0; kt < 8; ++kt) {
      short8 xfrag = *(const short8*)(Abuf + aBase + kt * 32);
#pragma unroll
      for (int nt = 0; nt < 8; ++nt) {
        int tile = (by * 8 + nt) * 8 + kt;      // nKt(Wxh)=8
        short8 wfrag = *(const short8*)(Wxh_p + (size_t)tile * 512 + lane * 8);
        acc[nt] = __builtin_amdgcn_mfma_f32_16x16x32_bf16(wfrag, xfrag, acc[nt], 0, 0, 0);
      }
    }
    unsigned short hv[32];
#pragma unroll
    for (int nt = 0; nt < 8; ++nt) {
      float4 bh4 = *(const float4*)(b_h + by * 128 + nt * 16 + quad * 4);
#pragma unroll
      for (int r = 0; r < 4; ++r)
        hv[nt * 4 + r] = f32_to_bf16(acc[nt][r] + (&bh4.x)[r]);
    }
    unsigned short* dst = xh_s + ((size_t)(t * 8 + g) * 4 + by) * 2048 + lane * 32;
#pragma unroll
    for (int k = 0; k < 4; ++k) {
      uint4 u;
      u.x = (unsigned)hv[k*8+0] | ((unsigned)hv[k*8+1] << 16);
      u.y = (unsigned)hv[k*8+2] | ((unsigned)hv[k*8+3] << 16);
      u.z = (unsigned)hv[k*8+4] | ((unsigned)hv[k*8+5] << 16);
      u.w = (unsigned)hv[k*8+6] | ((unsigned)hv[k*8+7] << 16);
      *(uint4*)(dst + k * 8) = u;
    }
  }
}

// ---------------------------------------------------------------------------
// Phase 2: recurrence. grid 16 (g = blockIdx&7, half = blockIdx>>3),
// block 512 = 8 waves (2/SIMD). Window (t,g) = xhs + (t*8+g)*8192 shorts:
//   xh input : half's bytes = by in {half*2, half*2+1} blocks of 2048 shorts
//   h output : frag F in [half*8, half*8+8) at F*512 + lane*8 (shorts)
// Wave W owns cols c0 = half*256 + W*32 -> writes exactly frag half*8+W.
// LDS: Hlds[t&1] holds h_{t-1} frags (global frag index 0..15) for step t.
// ---------------------------------------------------------------------------
__global__ __launch_bounds__(512, 2) void rnn_recurrence_kernel(
    const unsigned short* __restrict__ Whh_p,
    unsigned short* __restrict__ xhs,            // xh in, hs out (in-place)
    int* __restrict__ flags) {
  __shared__ __align__(16) unsigned short Hlds[2][16 * 512];   // 32 KB
  const int tid = threadIdx.x;
  const int W = tid >> 6, lane = tid & 63;
  const int quad = lane >> 4, col16 = lane & 15;
  const int g = blockIdx.x & 7, half = blockIdx.x >> 3;

  // 32 weight frags -> 128 AGPRs. wf[p*16+kk] holds tile
  // (NT = half*16 + W*2 + p, kt = (half*8+kk)&15): kk 0..7 = own-half kts,
  // kk 8..15 = partner-half kts. MFMA indices stay compile-time (rule #20).
  short8 wf[32];
#pragma unroll
  for (int p = 0; p < 2; ++p)
#pragma unroll
    for (int kk = 0; kk < 16; ++kk) {
      int kt = (half * 8 + kk) & 15;
      wf[p * 16 + kk] = *(const short8*)(
          Whh_p + ((size_t)((half * 16 + W * 2 + p) * 16 + kt)) * 512 + lane * 8);
    }
#pragma unroll
  for (int f = 0; f < 32; ++f) asm volatile("" : "+a"(wf[f]));

  int* flagSelf = flags + (g * 2 + half) * 32;
  int* flagPart = flags + (g * 2 + (half ^ 1)) * 32;

  // xh read: cols c0 + p*16 + quad*4 + r, c0 = half*256 + W*32 ->
  // by = half*2 + (W>>2); within-by nt = (W&3)*2 + p; one uint4 =
  // shorts [(W&3)*8 .. +8) of the lane*32 run, short index s = p*4+r.
  const unsigned short* xhL =
      xhs + (size_t)g * 8192 + (half * 2 + (W >> 2)) * 2048 + lane * 32 + (W & 3) * 8;

  // Frag store offsets (shorts): own frag F = half*8 + W; element position
  // lane' = (p*2 + (quad>>1))*16 + col16, j0 = (quad&1)*4:
  const int fragOwn = half * 8 + W;              // global frag index 0..15
  const int fragPart = (half ^ 1) * 8 + W;       // staged partner frag
  const int eIn = (quad >> 1) * 128 + col16 * 8 + (quad & 1) * 4;  // within-frag
  const int eBase = fragOwn * 512 + eIn;         // global h store (window-rel)

  // ---- t = 0: h_0 = tanh(xh[0]) (h_{-1} = 0) ----
  // R9 race fix: read xh[0] -> barrier (vmcnt drain) -> store h_0.
  uint4 xq = *(const uint4*)(xhL);
  __syncthreads();
  {
    unsigned short* winCur = xhs + (size_t)g * 8192;
    unsigned xw[4] = {xq.x, xq.y, xq.z, xq.w};
#pragma unroll
    for (int p = 0; p < 2; ++p) {
      float hv[4];
#pragma unroll
      for (int r = 0; r < 4; ++r) {
        unsigned uu = xw[p * 2 + (r >> 1)];
        float xv = (r & 1) ? bf16_hi(uu) : bf16_lo(uu);
        hv[r] = tanh_fast(xv);
      }
      uint2v o;
      o.x = cvt_pk_bf16(hv[0], hv[1]);
      o.y = cvt_pk_bf16(hv[2], hv[3]);
      *(uint2v*)(winCur + eBase + p * 256) = o;                 // global hs
      *(uint2v*)(&Hlds[1][fragOwn * 512 + eIn + p * 256]) = o;  // LDS buf[1]
    }
    __syncthreads();   // vmcnt+lgkm drain: h_0 in L2 and LDS
    if (tid == 0)
      __hip_atomic_store(flagSelf, 1, __ATOMIC_RELEASE, __HIP_MEMORY_SCOPE_AGENT);
  }
  // prefetch xh[1]
  xq = *(const uint4*)(xhL + 65536);

#pragma unroll 1
  for (int t = 1; t < 512; ++t) {
    const unsigned short* winPrev = xhs + ((size_t)(t - 1) * 8 + g) * 8192;
    unsigned short* winCur = xhs + ((size_t)t * 8 + g) * 8192;
    const unsigned short* bufR = Hlds[t & 1];
    unsigned short* bufW = Hlds[(t & 1) ^ 1];

    // Own-half h frags from LDS (written by all 8 waves last step; ordered
    // by the end-of-step barrier). Issue all 8 ds_reads up front.
    short8 hf[8];
#pragma unroll
    for (int kk = 0; kk < 8; ++kk)
      hf[kk] = *(const short8*)(bufR + (half * 8 + kk) * 512 + lane * 8);

    // Poll partner flag (relaxed; one acquire fence after). In lockstep it
    // is already set by now.
    while (__hip_atomic_load(flagPart, __ATOMIC_RELAXED, __HIP_MEMORY_SCOPE_AGENT) < t) {}
    __builtin_amdgcn_fence(__ATOMIC_ACQUIRE, "agent");

    // Stage this wave's 1KB share of the partner's h_{t-1} (one dwordx4).
    // Latency hides under acc-init + own-half MFMAs below.
    uint4 st = *(const uint4*)(winPrev + (size_t)fragPart * 512 + lane * 8);

    // acc init = xh[t] (bf16 unpack into fp32 accumulator).
    unsigned xw[4] = {xq.x, xq.y, xq.z, xq.w};
    f32x4 acc[2];
#pragma unroll
    for (int p = 0; p < 2; ++p)
#pragma unroll
      for (int r = 0; r < 4; ++r) {
        unsigned uu = xw[p * 2 + (r >> 1)];
        acc[p][r] = (r & 1) ? bf16_hi(uu) : bf16_lo(uu);
      }

    // Prefetch xh[t+1] into the now-dead xq register.
    xq = *(const uint4*)(xhL + (size_t)(t < 511 ? t + 1 : 511) * 65536);

    // Own-half MFMAs (cover the stage-load latency).
#pragma unroll
    for (int kk = 0; kk < 8; ++kk)
#pragma unroll
      for (int p = 0; p < 2; ++p)
        acc[p] = __builtin_amdgcn_mfma_f32_16x16x32_bf16(wf[p * 16 + kk], hf[kk], acc[p], 0, 0, 0);

    // Publish staged partner frag to LDS; barrier, then everyone reads it.
    *(uint4*)(&((unsigned short*)bufR)[fragPart * 512 + lane * 8]) = st;
    __syncthreads();

    short8 pf[8];
#pragma unroll
    for (int kk = 0; kk < 8; ++kk)
      pf[kk] = *(const short8*)(bufR + ((half ^ 1) * 8 + kk) * 512 + lane * 8);
#pragma unroll
    for (int kk = 0; kk < 8; ++kk)
#pragma unroll
      for (int p = 0; p < 2; ++p)
        acc[p] = __builtin_amdgcn_mfma_f32_16x16x32_bf16(wf[p * 16 + 8 + kk], pf[kk], acc[p], 0, 0, 0);

    // Epilogue: h_t = tanh(acc); store to global (partner + phase-3 output)
    // and to LDS next-buffer (own-half broadcast for step t+1).
#pragma unroll
    for (int p = 0; p < 2; ++p) {
      float t0 = tanh_fast(acc[p][0]);
      float t1 = tanh_fast(acc[p][1]);
      float t2 = tanh_fast(acc[p][2]);
      float t3 = tanh_fast(acc[p][3]);
      uint2v o;
      o.x = cvt_pk_bf16(t0, t1);
      o.y = cvt_pk_bf16(t2, t3);
      *(uint2v*)(winCur + eBase + p * 256) = o;
      *(uint2v*)(&bufW[fragOwn * 512 + eIn + p * 256]) = o;
    }

    // Barrier drains vmcnt (global h stores in L2) + lgkm (LDS writes);
    // the release store then publishes to the partner.
    __syncthreads();
    if (tid == 0)
      __hip_atomic_store(flagSelf, t + 1, __ATOMIC_RELEASE, __HIP_MEMORY_SCOPE_AGENT);
  }
}

// ---------------------------------------------------------------------------
// Phase 3: out = hs @ W_hy + b_y.  hs is in frag layout:
// window (m0>>4) at (m0>>4)*8192 shorts, frag kt at kt*512 + lane*8.
// ---------------------------------------------------------------------------
__global__ __launch_bounds__(256) void out_gemm_kernel(
    const unsigned short* __restrict__ hs, const unsigned short* __restrict__ Why_p,
    const float* __restrict__ b_y, float* __restrict__ out) {
  const int tid = threadIdx.x;
  const int w = tid >> 6, lane = tid & 63;
  const int quad = lane >> 4, col16 = lane & 15;
  const int m0 = blockIdx.x * 64 + w * 16;

  f32x4 acc[8];
#pragma unroll
  for (int nt = 0; nt < 8; ++nt) acc[nt] = (f32x4){0.f,0.f,0.f,0.f};

  const unsigned short* aP = hs + (size_t)(m0 >> 4) * 8192 + lane * 8;
#pragma unroll
  for (int kt = 0; kt < 16; ++kt) {
    short8 a = *(const short8*)(aP + kt * 512);
#pragma unroll
    for (int nt = 0; nt < 8; ++nt) {
      int tile = nt * 16 + kt;                 // nKt(Why)=16
      short8 b = *(const short8*)(Why_p + (size_t)tile * 512 + lane * 8);
      acc[nt] = __builtin_amdgcn_mfma_f32_16x16x32_bf16(a, b, acc[nt], 0, 0, 0);
    }
  }
#pragma unroll
  for (int nt = 0; nt < 8; ++nt) {
    int n = nt * 16 + col16;
    float by = b_y[n];
#pragma unroll
    for (int r = 0; r < 4; ++r)
      out[(size_t)(m0 + quad * 4 + r) * 128 + n] = acc[nt][r] + by;
  }
}

// ---------------------------------------------------------------------------
extern "C" void kernel_launch(void* const* d_in, const int* in_sizes, int n_in,
                              void* d_out, int out_size, void* d_ws, size_t ws_size,
                              hipStream_t stream) {
  const float* x    = (const float*)d_in[0];   // [512,128,256]
  const float* W_xh = (const float*)d_in[1];   // [256,512]
  const float* W_hh = (const float*)d_in[2];   // [512,512]
  const float* W_hy = (const float*)d_in[3];   // [512,128]
  const float* b_h  = (const float*)d_in[4];   // [512]
  const float* b_y  = (const float*)d_in[5];   // [128]
  float* out = (float*)d_out;                  // [512,128,128]

  char* ws = (char*)d_ws;
  unsigned short* Wxh_p = (unsigned short*)(ws);                 // 256 KB
  unsigned short* Whh_p = (unsigned short*)(ws + (256 << 10));   // 512 KB
  unsigned short* Why_p = (unsigned short*)(ws + (768 << 10));   // 128 KB
  int*            flags = (int*)(ws + (960 << 10));              // 2 KB
  unsigned short* xhs   = (unsigned short*)(ws + (1024 << 10));  // 64 MB

  pack_b_kernel<<<64, 256, 0, stream>>>(W_xh, Wxh_p, 256, 512);
  pack_b_kernel<<<128, 256, 0, stream>>>(W_hh, Whh_p, 512, 512);
  pack_b_kernel<<<32, 256, 0, stream>>>(W_hy, Why_p, 512, 128);
  init_flags_kernel<<<1, 64, 0, stream>>>(flags);

  xh_gemm_kernel<<<1024, 256, 0, stream>>>(x, Wxh_p, b_h, xhs);

  rnn_recurrence_kernel<<<16, 512, 0, stream>>>(Whh_p, xhs, flags);

  out_gemm_kernel<<<1024, 256, 0, stream>>>(xhs, Why_p, b_y, out);
}

// Round 8
// 1149.427 us; speedup vs baseline: 1.4053x; 1.4053x over previous
//
#include <hip/hip_runtime.h>

// RNN: S=512, B=128, I=256, H=512, O=128
// R12 = R11 + hang-proof XCD handshake. R11's bench died with a container
// failure consistent with a deadlock: the XCC-ID handshake used RELAXED
// agent atomics both sides; relaxed stores can sit dirty in the local L2
// (not cross-XCD visible) -> partner spins on -1 forever. Fix:
//   - ID publish = RELEASE store, poll = ACQUIRE loads (the proven
//     cross-XCD-visible pair; one-time cost).
//   - Bounded spin (1M iters); timeout -> slow path (fenced protocol,
//     correct on any mapping). fast=true only on OBSERVED id equality.
// R11 (kept): per-step agent-fence elision when the (g,g+8) pair shares an
// XCD. Theory: agent ACQ fence = vmcnt+L2-invalidate, REL = wbL2; 512x
// wb+inv of 4MB L2 per dispatch is the serial cost AND evicts streamed xh
// (FETCH 35MB anomaly); explains R9==R10 null (placement can't matter if
// L2 is flushed每step). Same-XCD: shared L2 is the coherence point; barrier
// vmcnt drain + in-order flag store suffice; partner loads plain b128
// (L1-cold by construction). One barrier/step.
// R10 (kept): own-half h frags broadcast via LDS double-buffer.
// R9 (kept): t=0 read->barrier->store race fix. R8 (kept): 8 waves (2/SIMD),
// 32 W_hh frags = 128 AGPRs/wave, wave W owns cols half*256+W*32 == frag
// half*8+W. R7 (kept): relaxed step-flag poll; poll at step top. R5 (kept):
// fast tanh, v_cvt_pk_bf16_f32, xh folded into acc init + 1-step prefetch.

typedef __attribute__((ext_vector_type(8))) short short8;   // 8 bf16
typedef __attribute__((ext_vector_type(4))) float f32x4;    // MFMA C/D
typedef __attribute__((ext_vector_type(2))) unsigned int uint2v;

__device__ __forceinline__ unsigned short f32_to_bf16(float f) {
  unsigned int u = __float_as_uint(f);
  u += 0x7FFFu + ((u >> 16) & 1u);
  return (unsigned short)(u >> 16);
}

// tanh(x) = 1 - 2/(e^{2x}+1) = 1 - 2*rcp(2^{2*log2e*x}+1).
__device__ __forceinline__ float tanh_fast(float x) {
  float e = __builtin_amdgcn_exp2f(x * 2.885390081777927f);  // 2*log2(e)
  float r = __builtin_amdgcn_rcpf(e + 1.0f);
  return __builtin_fmaf(-2.0f, r, 1.0f);
}

// D[15:0] = bf16(lo), D[31:16] = bf16(hi)
__device__ __forceinline__ unsigned cvt_pk_bf16(float lo, float hi) {
  unsigned r;
  asm("v_cvt_pk_bf16_f32 %0, %1, %2" : "=v"(r) : "v"(lo), "v"(hi));
  return r;
}

__device__ __forceinline__ float bf16_lo(unsigned u) {
  return __uint_as_float(u << 16);
}
__device__ __forceinline__ float bf16_hi(unsigned u) {
  return __uint_as_float(u & 0xFFFF0000u);
}

// ---------------------------------------------------------------------------
// Pack K x N fp32 row-major -> bf16 MFMA fragment tiles.
// Tile (nt,kt): lane holds W[k=kt*32+(lane>>4)*8+j][n=nt*16+(lane&15)],
// stored P[tile*512 + lane*8 + j], tile = nt*(K/32)+kt.
// ---------------------------------------------------------------------------
__global__ void pack_b_kernel(const float* __restrict__ W,
                              unsigned short* __restrict__ P, int K, int N) {
  int tid  = blockIdx.x * 256 + threadIdx.x;
  int lane = tid & 63;
  int tile = tid >> 6;
  int nKt  = K >> 5;
  int nTiles = (N >> 4) * nKt;
  if (tile >= nTiles) return;
  int nt = tile / nKt;
  int kt = tile - nt * nKt;
  int n  = (nt << 4) + (lane & 15);
  int k0 = (kt << 5) + ((lane >> 4) << 3);
  unsigned short* dst = P + (size_t)tile * 512 + lane * 8;
#pragma unroll
  for (int j = 0; j < 8; ++j)
    dst[j] = f32_to_bf16(W[(size_t)(k0 + j) * N + n]);
}

// flags[(g*2+half)*32 + 0] = step flag; [+1] = XCC id (sentinel -1).
__global__ void init_flags_kernel(int* __restrict__ flags) {
  if (threadIdx.x < 16) {
    flags[threadIdx.x * 32] = 0;
    flags[threadIdx.x * 32 + 1] = -1;
  }
}

// ---------------------------------------------------------------------------
// Phase 1: xh = x@W_xh + b_h, swapped-operand MFMA; stored pre-swizzled:
// xh_s[((t*8+g)*4 + by)*2048 + lane*32 + nt*4 + r] =
//   xh[t][g*16 + (lane&15)][by*128 + nt*16 + (lane>>4)*4 + r]
// grid 1024; by-loop internal so x is read from HBM exactly once.
// ---------------------------------------------------------------------------
__global__ __launch_bounds__(256) void xh_gemm_kernel(
    const float* __restrict__ x, const unsigned short* __restrict__ Wxh_p,
    const float* __restrict__ b_h, unsigned short* __restrict__ xh_s) {
  __shared__ __align__(16) unsigned short Abuf[64 * 264];
  const int tid = threadIdx.x;
  const int m0 = blockIdx.x * 64;

#pragma unroll
  for (int i = 0; i < 16; ++i) {
    int flat = i * 1024 + tid * 4;
    int row = flat >> 8, col = flat & 255;
    float4 v = *(const float4*)(x + (size_t)(m0 + row) * 256 + col);
    ushort4 u;
    u.x = f32_to_bf16(v.x); u.y = f32_to_bf16(v.y);
    u.z = f32_to_bf16(v.z); u.w = f32_to_bf16(v.w);
    *(ushort4*)(Abuf + row * 264 + col) = u;
  }
  __syncthreads();

  const int w2 = tid >> 6, lane = tid & 63;
  const int quad = lane >> 4, col16 = lane & 15;
  const int aBase = (w2 * 16 + col16) * 264 + quad * 8;
  const int t = (m0 + w2 * 16) >> 7;
  const int g = ((m0 + w2 * 16) & 127) >> 4;

  for (int by = 0; by < 4; ++by) {
    f32x4 acc[8];
#pragma unroll
    for (int nt = 0; nt < 8; ++nt) acc[nt] = (f32x4){0.f,0.f,0.f,0.f};
#pragma unroll
    for (int kt = 0; kt < 8; ++kt) {
      short8 xfrag = *(const short8*)(Abuf + aBase + kt * 32);
#pragma unroll
      for (int nt = 0; nt < 8; ++nt) {
        int tile = (by * 8 + nt) * 8 + kt;      // nKt(Wxh)=8
        short8 wfrag = *(const short8*)(Wxh_p + (size_t)tile * 512 + lane * 8);
        acc[nt] = __builtin_amdgcn_mfma_f32_16x16x32_bf16(wfrag, xfrag, acc[nt], 0, 0, 0);
      }
    }
    unsigned short hv[32];
#pragma unroll
    for (int nt = 0; nt < 8; ++nt) {
      float4 bh4 = *(const float4*)(b_h + by * 128 + nt * 16 + quad * 4);
#pragma unroll
      for (int r = 0; r < 4; ++r)
        hv[nt * 4 + r] = f32_to_bf16(acc[nt][r] + (&bh4.x)[r]);
    }
    unsigned short* dst = xh_s + ((size_t)(t * 8 + g) * 4 + by) * 2048 + lane * 32;
#pragma unroll
    for (int k = 0; k < 4; ++k) {
      uint4 u;
      u.x = (unsigned)hv[k*8+0] | ((unsigned)hv[k*8+1] << 16);
      u.y = (unsigned)hv[k*8+2] | ((unsigned)hv[k*8+3] << 16);
      u.z = (unsigned)hv[k*8+4] | ((unsigned)hv[k*8+5] << 16);
      u.w = (unsigned)hv[k*8+6] | ((unsigned)hv[k*8+7] << 16);
      *(uint4*)(dst + k * 8) = u;
    }
  }
}

// ---------------------------------------------------------------------------
// Phase 2: recurrence. grid 16 (g = blockIdx&7, half = blockIdx>>3),
// block 512 = 8 waves (2/SIMD). Window (t,g) = xhs + (t*8+g)*8192 shorts:
//   xh input : half's bytes = by in {half*2, half*2+1} blocks of 2048 shorts
//   h output : frag F in [half*8, half*8+8) at F*512 + lane*8 (shorts)
// Wave W owns cols c0 = half*256 + W*32 -> writes exactly frag half*8+W.
// LDS: Hlds[t&1] holds own-half h_{t-1} frags for step t.
// ---------------------------------------------------------------------------
__global__ __launch_bounds__(512, 2) void rnn_recurrence_kernel(
    const unsigned short* __restrict__ Whh_p,
    unsigned short* __restrict__ xhs,            // xh in, hs out (in-place)
    int* __restrict__ flags) {
  __shared__ __align__(16) unsigned short Hlds[2][16 * 512];   // 32 KB
  __shared__ int fastSh;
  const int tid = threadIdx.x;
  const int W = tid >> 6, lane = tid & 63;
  const int quad = lane >> 4, col16 = lane & 15;
  const int g = blockIdx.x & 7, half = blockIdx.x >> 3;

  // ---- XCD handshake (hang-proof): RELEASE publish + ACQUIRE poll with a
  // bounded spin. fast=true only on OBSERVED id equality; timeout -> slow.
  int myx;
  asm volatile("s_getreg_b32 %0, hwreg(HW_REG_XCC_ID)" : "=s"(myx));
  if (tid == 0) {
    __hip_atomic_store(&flags[(g * 2 + half) * 32 + 1], myx,
                       __ATOMIC_RELEASE, __HIP_MEMORY_SCOPE_AGENT);
    int pv = -1;
    for (int spin = 0; spin < (1 << 20) && pv == -1; ++spin)
      pv = __hip_atomic_load(&flags[(g * 2 + (half ^ 1)) * 32 + 1],
                             __ATOMIC_ACQUIRE, __HIP_MEMORY_SCOPE_AGENT);
    fastSh = (pv == myx);
  }

  // 32 weight frags -> 128 AGPRs. wf[p*16+kk] holds tile
  // (NT = half*16 + W*2 + p, kt = (half*8+kk)&15): kk 0..7 = own-half kts,
  // kk 8..15 = partner-half kts. MFMA indices stay compile-time (rule #20).
  short8 wf[32];
#pragma unroll
  for (int p = 0; p < 2; ++p)
#pragma unroll
    for (int kk = 0; kk < 16; ++kk) {
      int kt = (half * 8 + kk) & 15;
      wf[p * 16 + kk] = *(const short8*)(
          Whh_p + ((size_t)((half * 16 + W * 2 + p) * 16 + kt)) * 512 + lane * 8);
    }
#pragma unroll
  for (int f = 0; f < 32; ++f) asm volatile("" : "+a"(wf[f]));

  int* flagSelf = flags + (g * 2 + half) * 32;
  int* flagPart = flags + (g * 2 + (half ^ 1)) * 32;

  // xh read: cols c0 + p*16 + quad*4 + r, c0 = half*256 + W*32 ->
  // by = half*2 + (W>>2); within-by nt = (W&3)*2 + p; one uint4 =
  // shorts [(W&3)*8 .. +8) of the lane*32 run, short index s = p*4+r.
  const unsigned short* xhL =
      xhs + (size_t)g * 8192 + (half * 2 + (W >> 2)) * 2048 + lane * 32 + (W & 3) * 8;

  // Frag store offsets (shorts): own frag F = half*8 + W; element position
  // lane' = (p*2 + (quad>>1))*16 + col16, j0 = (quad&1)*4:
  const int fragOwn = half * 8 + W;              // global frag index 0..15
  const int eIn = (quad >> 1) * 128 + col16 * 8 + (quad & 1) * 4;  // within-frag
  const int eBase = fragOwn * 512 + eIn;         // global h store (window-rel)

  // ---- t = 0: h_0 = tanh(xh[0]) (h_{-1} = 0) ----
  // R9 race fix: read xh[0] -> barrier (vmcnt drain) -> store h_0.
  // (This barrier also publishes fastSh.)
  uint4 xq = *(const uint4*)(xhL);
  __syncthreads();
  const bool fast = (fastSh != 0);
  {
    unsigned short* winCur = xhs + (size_t)g * 8192;
    unsigned xw[4] = {xq.x, xq.y, xq.z, xq.w};
#pragma unroll
    for (int p = 0; p < 2; ++p) {
      float hv[4];
#pragma unroll
      for (int r = 0; r < 4; ++r) {
        unsigned uu = xw[p * 2 + (r >> 1)];
        float xv = (r & 1) ? bf16_hi(uu) : bf16_lo(uu);
        hv[r] = tanh_fast(xv);
      }
      uint2v o;
      o.x = cvt_pk_bf16(hv[0], hv[1]);
      o.y = cvt_pk_bf16(hv[2], hv[3]);
      *(uint2v*)(winCur + eBase + p * 256) = o;                 // global hs
      *(uint2v*)(&Hlds[1][fragOwn * 512 + eIn + p * 256]) = o;  // LDS buf[1]
    }
    __syncthreads();   // vmcnt+lgkm drain: h_0 in L2 and LDS
    if (tid == 0) {
      if (!fast) __builtin_amdgcn_fence(__ATOMIC_RELEASE, "agent");
      __hip_atomic_store(flagSelf, 1, __ATOMIC_RELAXED, __HIP_MEMORY_SCOPE_AGENT);
    }
  }
  // prefetch xh[1]
  xq = *(const uint4*)(xhL + 65536);

#pragma unroll 1
  for (int t = 1; t < 512; ++t) {
    const unsigned short* winPrev = xhs + ((size_t)(t - 1) * 8 + g) * 8192;
    unsigned short* winCur = xhs + ((size_t)t * 8 + g) * 8192;
    const unsigned short* bufR = Hlds[t & 1];
    unsigned short* bufW = Hlds[(t & 1) ^ 1];

    // Own-half h frags from LDS (written by all 8 waves last step; ordered
    // by the end-of-step barrier). Issue all 8 ds_reads up front (lgkm --
    // unaffected by the conditional fence's vmcnt drain).
    short8 hf[8];
#pragma unroll
    for (int kk = 0; kk < 8; ++kk)
      hf[kk] = *(const short8*)(bufR + (half * 8 + kk) * 512 + lane * 8);

    // Poll partner flag (relaxed sc0 load; in lockstep already set).
    while (__hip_atomic_load(flagPart, __ATOMIC_RELAXED, __HIP_MEMORY_SCOPE_AGENT) < t) {}
    if (!fast) __builtin_amdgcn_fence(__ATOMIC_ACQUIRE, "agent");
    asm volatile("" ::: "memory");   // no compiler hoist of loads above poll

    // Partner h frags: direct PLAIN b128 loads. Fast path coherence: lines
    // are L1-cold by construction (each winPrev region read exactly once
    // ever by this CU), so they fetch from the shared same-XCD L2, which
    // holds the partner's barrier-drained stores. Latency covered by acc
    // init + own-half MFMAs below.
    short8 pf[8];
#pragma unroll
    for (int kk = 0; kk < 8; ++kk)
      pf[kk] = *(const short8*)(winPrev + ((half ^ 1) * 8 + kk) * 512 + lane * 8);

    // acc init = xh[t] (bf16 unpack into fp32 accumulator).
    unsigned xw[4] = {xq.x, xq.y, xq.z, xq.w};
    f32x4 acc[2];
#pragma unroll
    for (int p = 0; p < 2; ++p)
#pragma unroll
      for (int r = 0; r < 4; ++r) {
        unsigned uu = xw[p * 2 + (r >> 1)];
        acc[p][r] = (r & 1) ? bf16_hi(uu) : bf16_lo(uu);
      }

    // Prefetch xh[t+1] into the now-dead xq register (HBM latency covered
    // by the rest of the step; drained at the end barrier).
    xq = *(const uint4*)(xhL + (size_t)(t < 511 ? t + 1 : 511) * 65536);

    // Own-half MFMAs (cover the partner-load latency).
#pragma unroll
    for (int kk = 0; kk < 8; ++kk)
#pragma unroll
      for (int p = 0; p < 2; ++p)
        acc[p] = __builtin_amdgcn_mfma_f32_16x16x32_bf16(wf[p * 16 + kk], hf[kk], acc[p], 0, 0, 0);

    // Partner-half MFMAs.
#pragma unroll
    for (int kk = 0; kk < 8; ++kk)
#pragma unroll
      for (int p = 0; p < 2; ++p)
        acc[p] = __builtin_amdgcn_mfma_f32_16x16x32_bf16(wf[p * 16 + 8 + kk], pf[kk], acc[p], 0, 0, 0);

    // Epilogue: h_t = tanh(acc); store to global (partner + phase-3 output)
    // and to LDS next-buffer (own-half broadcast for step t+1).
#pragma unroll
    for (int p = 0; p < 2; ++p) {
      float t0 = tanh_fast(acc[p][0]);
      float t1 = tanh_fast(acc[p][1]);
      float t2 = tanh_fast(acc[p][2]);
      float t3 = tanh_fast(acc[p][3]);
      uint2v o;
      o.x = cvt_pk_bf16(t0, t1);
      o.y = cvt_pk_bf16(t2, t3);
      *(uint2v*)(winCur + eBase + p * 256) = o;
      *(uint2v*)(&bufW[fragOwn * 512 + eIn + p * 256]) = o;
    }

    // Single barrier: drains vmcnt (global h stores ack'd in L2) + lgkm
    // (LDS writes) for ALL waves, then tid0 publishes. Fast path: plain
    // relaxed flag store (same-XCD L2 order suffices). Slow path: release
    // fence (wbL2) first.
    __syncthreads();
    if (tid == 0) {
      if (!fast) __builtin_amdgcn_fence(__ATOMIC_RELEASE, "agent");
      __hip_atomic_store(flagSelf, t + 1, __ATOMIC_RELAXED, __HIP_MEMORY_SCOPE_AGENT);
    }
  }
}

// ---------------------------------------------------------------------------
// Phase 3: out = hs @ W_hy + b_y.  hs is in frag layout:
// window (m0>>4) at (m0>>4)*8192 shorts, frag kt at kt*512 + lane*8.
// ---------------------------------------------------------------------------
__global__ __launch_bounds__(256) void out_gemm_kernel(
    const unsigned short* __restrict__ hs, const unsigned short* __restrict__ Why_p,
    const float* __restrict__ b_y, float* __restrict__ out) {
  const int tid = threadIdx.x;
  const int w = tid >> 6, lane = tid & 63;
  const int quad = lane >> 4, col16 = lane & 15;
  const int m0 = blockIdx.x * 64 + w * 16;

  f32x4 acc[8];
#pragma unroll
  for (int nt = 0; nt < 8; ++nt) acc[nt] = (f32x4){0.f,0.f,0.f,0.f};

  const unsigned short* aP = hs + (size_t)(m0 >> 4) * 8192 + lane * 8;
#pragma unroll
  for (int kt = 0; kt < 16; ++kt) {
    short8 a = *(const short8*)(aP + kt * 512);
#pragma unroll
    for (int nt = 0; nt < 8; ++nt) {
      int tile = nt * 16 + kt;                 // nKt(Why)=16
      short8 b = *(const short8*)(Why_p + (size_t)tile * 512 + lane * 8);
      acc[nt] = __builtin_amdgcn_mfma_f32_16x16x32_bf16(a, b, acc[nt], 0, 0, 0);
    }
  }
#pragma unroll
  for (int nt = 0; nt < 8; ++nt) {
    int n = nt * 16 + col16;
    float by = b_y[n];
#pragma unroll
    for (int r = 0; r < 4; ++r)
      out[(size_t)(m0 + quad * 4 + r) * 128 + n] = acc[nt][r] + by;
  }
}

// ---------------------------------------------------------------------------
extern "C" void kernel_launch(void* const* d_in, const int* in_sizes, int n_in,
                              void* d_out, int out_size, void* d_ws, size_t ws_size,
                              hipStream_t stream) {
  const float* x    = (const float*)d_in[0];   // [512,128,256]
  const float* W_xh = (const float*)d_in[1];   // [256,512]
  const float* W_hh = (const float*)d_in[2];   // [512,512]
  const float* W_hy = (const float*)d_in[3];   // [512,128]
  const float* b_h  = (const float*)d_in[4];   // [512]
  const float* b_y  = (const float*)d_in[5];   // [128]
  float* out = (float*)d_out;                  // [512,128,128]

  char* ws = (char*)d_ws;
  unsigned short* Wxh_p = (unsigned short*)(ws);                 // 256 KB
  unsigned short* Whh_p = (unsigned short*)(ws + (256 << 10));   // 512 KB
  unsigned short* Why_p = (unsigned short*)(ws + (768 << 10));   // 128 KB
  int*            flags = (int*)(ws + (960 << 10));              // 2 KB
  unsigned short* xhs   = (unsigned short*)(ws + (1024 << 10));  // 64 MB

  pack_b_kernel<<<64, 256, 0, stream>>>(W_xh, Wxh_p, 256, 512);
  pack_b_kernel<<<128, 256, 0, stream>>>(W_hh, Whh_p, 512, 512);
  pack_b_kernel<<<32, 256, 0, stream>>>(W_hy, Why_p, 512, 128);
  init_flags_kernel<<<1, 64, 0, stream>>>(flags);

  xh_gemm_kernel<<<1024, 256, 0, stream>>>(x, Wxh_p, b_h, xhs);

  rnn_recurrence_kernel<<<16, 512, 0, stream>>>(Whh_p, xhs, flags);

  out_gemm_kernel<<<1024, 256, 0, stream>>>(xhs, Why_p, b_y, out);
}